// Round 4
// baseline (564.084 us; speedup 1.0000x reference)
//
#include <hip/hip_runtime.h>
#include <hip/hip_bf16.h>

#define N_NODES 100000
#define N_EDGES 1250000
#define D_FEAT  64

#define BW        128                            // nodes per coarse bucket
#define NBK       ((N_NODES + BW - 1) / BW)      // 782 buckets
#define SCAP      16                             // LDS staging entries/bucket
#define CHUNK     4096                           // edges per block, pass 1
#define PASS1_T   512
#define BCAP      1792                           // global entries per bucket (mean 1600, +4.8 sigma)
#define SPILL_CAP 65536

// ---------------- pass 1: bin edges by dst bucket, LDS write-combined ----------------
// record = (src << 7) | (dst & 127)   (src < 2^17, so 24 bits total)
__global__ __launch_bounds__(PASS1_T)
void k_bin(const int* __restrict__ src, const int* __restrict__ dst,
           int* __restrict__ bucket_cnt, unsigned* __restrict__ buckets,
           int* __restrict__ spill_cnt, int* __restrict__ spill) {
    __shared__ int      stg_cnt[NBK];        // 3.1 KB
    __shared__ unsigned stg[NBK][SCAP];      // 50 KB
    int tid = threadIdx.x;
    for (int i = tid; i < NBK; i += PASS1_T) stg_cnt[i] = 0;
    __syncthreads();

    int base = blockIdx.x * CHUNK;
    #pragma unroll
    for (int r = 0; r < CHUNK / PASS1_T; ++r) {
        int e = base + r * PASS1_T + tid;
        if (e < N_EDGES) {
            int d = dst[e], s = src[e];
            int b = d >> 7;
            int pos = atomicAdd(&stg_cnt[b], 1);
            unsigned rec = ((unsigned)s << 7) | (unsigned)(d & (BW - 1));
            if (pos < SCAP) {
                stg[b][pos] = rec;
            } else {                               // staging overflow (rare)
                int sp = atomicAdd(spill_cnt, 1);
                if (sp < SPILL_CAP) { spill[2 * sp] = d; spill[2 * sp + 1] = s; }
            }
        }
    }
    __syncthreads();

    // drain: one global atomic + short contiguous burst per non-empty bucket
    for (int b = tid; b < NBK; b += PASS1_T) {
        int cnt = stg_cnt[b];
        if (cnt > SCAP) cnt = SCAP;
        if (cnt > 0) {
            int gbase = atomicAdd(&bucket_cnt[b], cnt);
            for (int k = 0; k < cnt; ++k) {
                int gp = gbase + k;
                unsigned rec = stg[b][k];
                if (gp < BCAP) {
                    buckets[(long long)b * BCAP + gp] = rec;
                } else {                           // bucket overflow (rare)
                    int sp = atomicAdd(spill_cnt, 1);
                    if (sp < SPILL_CAP) {
                        spill[2 * sp]     = b * BW + (int)(rec & (BW - 1));
                        spill[2 * sp + 1] = (int)(rec >> 7);
                    }
                }
            }
        }
    }
}

// ---------------- pass 2: per-bucket gather + LDS f32 accumulate ----------------
__global__ __launch_bounds__(512)
void k_acc(const float* __restrict__ x, const int* __restrict__ bucket_cnt,
           const unsigned* __restrict__ buckets, float* __restrict__ out) {
    __shared__ float acc[BW * D_FEAT];           // 32 KB
    int tid = threadIdx.x;
    for (int i = tid; i < BW * D_FEAT; i += 512) acc[i] = 0.f;
    __syncthreads();

    int b = blockIdx.x;
    int cnt = bucket_cnt[b];
    if (cnt > BCAP) cnt = BCAP;
    const unsigned* bk = buckets + (long long)b * BCAP;
    int wid = tid >> 6, lane = tid & 63;

    int k = wid;                                  // waves stride 8, 4-way unroll
    for (; k + 24 < cnt; k += 32) {
        unsigned e0 = bk[k], e1 = bk[k + 8], e2 = bk[k + 16], e3 = bk[k + 24];
        float v0 = x[(e0 >> 7) * D_FEAT + lane];
        float v1 = x[(e1 >> 7) * D_FEAT + lane];
        float v2 = x[(e2 >> 7) * D_FEAT + lane];
        float v3 = x[(e3 >> 7) * D_FEAT + lane];
        atomicAdd(&acc[(e0 & (BW - 1)) * D_FEAT + lane], v0);
        atomicAdd(&acc[(e1 & (BW - 1)) * D_FEAT + lane], v1);
        atomicAdd(&acc[(e2 & (BW - 1)) * D_FEAT + lane], v2);
        atomicAdd(&acc[(e3 & (BW - 1)) * D_FEAT + lane], v3);
    }
    for (; k < cnt; k += 8) {
        unsigned e0 = bk[k];
        float v0 = x[(e0 >> 7) * D_FEAT + lane];
        atomicAdd(&acc[(e0 & (BW - 1)) * D_FEAT + lane], v0);
    }
    __syncthreads();

    long long n0 = (long long)b * BW;
    for (int i = tid; i < BW * D_FEAT; i += 512) {
        long long n = n0 + (i >> 6);
        if (n < N_NODES) out[n * D_FEAT + (i & 63)] = acc[i];
    }
}

// ---------------- pass 3: rare spilled edges via atomics ----------------
__global__ __launch_bounds__(256)
void k_spill(const float* __restrict__ x, const int* __restrict__ spill_cnt,
             const int* __restrict__ spill, float* __restrict__ out) {
    int sc = *spill_cnt;
    if (sc > SPILL_CAP) sc = SPILL_CAP;
    int total = sc * D_FEAT;
    int stride = gridDim.x * blockDim.x;
    for (int i = blockIdx.x * blockDim.x + threadIdx.x; i < total; i += stride) {
        int p = i >> 6, f = i & 63;
        int d = spill[2 * p], s = spill[2 * p + 1];
        atomicAdd(&out[(long long)d * D_FEAT + f], x[(long long)s * D_FEAT + f]);
    }
}

// ---------------- fallback: direct atomic scatter ----------------
__global__ __launch_bounds__(256)
void mp_scatter_atomic(const float* __restrict__ x,
                       const int* __restrict__ src,
                       const int* __restrict__ dst,
                       float* __restrict__ out) {
    long long t = (long long)blockIdx.x * blockDim.x + threadIdx.x;
    long long e = t >> 6;
    int f = (int)(t & 63);
    if (e >= N_EDGES) return;
    atomicAdd(&out[(long long)dst[e] * D_FEAT + f],
              x[(long long)src[e] * D_FEAT + f]);
}

extern "C" void kernel_launch(void* const* d_in, const int* in_sizes, int n_in,
                              void* d_out, int out_size, void* d_ws, size_t ws_size,
                              hipStream_t stream) {
    const float* x   = (const float*)d_in[0];
    const int*   ei  = (const int*)d_in[1];   // (2, N_EDGES): row 0 = src, row 1 = dst
    const int*   src = ei;
    const int*   dst = ei + N_EDGES;
    float* out = (float*)d_out;

    // ws layout (ints): bucket_cnt[NBK] | spill_cnt[1] | spill[2*SPILL_CAP] | (align) | buckets[NBK*BCAP]
    const size_t BK_OFF   = ((size_t)NBK + 1 + 2 * SPILL_CAP + 63) & ~(size_t)63;
    const size_t WS_INTS  = BK_OFF + (size_t)NBK * BCAP;
    const size_t WS_BYTES = WS_INTS * sizeof(int);   // ~6.1 MB

    if (ws_size >= WS_BYTES) {
        int*      wsi        = (int*)d_ws;
        int*      bucket_cnt = wsi;
        int*      spill_cnt  = wsi + NBK;
        int*      spill      = wsi + NBK + 1;
        unsigned* buckets    = (unsigned*)(wsi + BK_OFF);

        hipMemsetAsync(bucket_cnt, 0, (size_t)(NBK + 1) * sizeof(int), stream);

        int grid_bin = (N_EDGES + CHUNK - 1) / CHUNK;     // 306
        k_bin<<<grid_bin, PASS1_T, 0, stream>>>(src, dst, bucket_cnt, buckets,
                                                spill_cnt, spill);

        k_acc<<<NBK, 512, 0, stream>>>(x, bucket_cnt, buckets, out);

        k_spill<<<32, 256, 0, stream>>>(x, spill_cnt, spill, out);
    } else {
        hipMemsetAsync(out, 0, (size_t)out_size * sizeof(float), stream);
        long long total = (long long)N_EDGES * D_FEAT;
        int block = 256;
        long long grid = (total + block - 1) / block;
        mp_scatter_atomic<<<(dim3)(unsigned)grid, block, 0, stream>>>(x, src, dst, out);
    }
}

// Round 5
// 84.203 us; speedup vs baseline: 6.6991x; 6.6991x over previous
//
#include <hip/hip_runtime.h>
#include <hip/hip_bf16.h>

#define N_NODES 100000
#define N_EDGES 1250000
#define D_FEAT  64

#define BW        128                            // nodes per coarse bucket
#define NBK       ((N_NODES + BW - 1) / BW)      // 782 buckets
#define SCAP      16                             // LDS staging entries/bucket
#define CHUNK     4096                           // edges per block, pass 1
#define PASS1_T   512
#define BCAP      1792                           // global entries per bucket (mean 1600, +4.8 sigma)
#define SPILL_CAP 65536

// ---------------- pass 1: bin edges by dst bucket, LDS write-combined ----------------
// record = (src << 7) | (dst & 127)   (src < 2^17, so 24 bits total)
__global__ __launch_bounds__(PASS1_T)
void k_bin(const int* __restrict__ src, const int* __restrict__ dst,
           int* __restrict__ bucket_cnt, unsigned* __restrict__ buckets,
           int* __restrict__ spill_cnt, int* __restrict__ spill) {
    __shared__ int      stg_cnt[NBK];        // 3.1 KB
    __shared__ unsigned stg[NBK][SCAP];      // 50 KB
    int tid = threadIdx.x;
    for (int i = tid; i < NBK; i += PASS1_T) stg_cnt[i] = 0;
    __syncthreads();

    int base = blockIdx.x * CHUNK;
    #pragma unroll
    for (int r = 0; r < CHUNK / PASS1_T; ++r) {
        int e = base + r * PASS1_T + tid;
        if (e < N_EDGES) {
            int d = dst[e], s = src[e];
            int b = d >> 7;
            int pos = atomicAdd(&stg_cnt[b], 1);
            unsigned rec = ((unsigned)s << 7) | (unsigned)(d & (BW - 1));
            if (pos < SCAP) {
                stg[b][pos] = rec;
            } else {                               // staging overflow (rare)
                int sp = atomicAdd(spill_cnt, 1);
                if (sp < SPILL_CAP) { spill[2 * sp] = d; spill[2 * sp + 1] = s; }
            }
        }
    }
    __syncthreads();

    // drain: one global atomic + short contiguous burst per non-empty bucket
    for (int b = tid; b < NBK; b += PASS1_T) {
        int cnt = stg_cnt[b];
        if (cnt > SCAP) cnt = SCAP;
        if (cnt > 0) {
            int gbase = atomicAdd(&bucket_cnt[b], cnt);
            for (int k = 0; k < cnt; ++k) {
                int gp = gbase + k;
                unsigned rec = stg[b][k];
                if (gp < BCAP) {
                    buckets[(long long)b * BCAP + gp] = rec;
                } else {                           // bucket overflow (rare)
                    int sp = atomicAdd(spill_cnt, 1);
                    if (sp < SPILL_CAP) {
                        spill[2 * sp]     = b * BW + (int)(rec & (BW - 1));
                        spill[2 * sp + 1] = (int)(rec >> 7);
                    }
                }
            }
        }
    }
}

// ---------------- pass 2: per-bucket counting sort (LDS) + register accumulate ----------------
__global__ __launch_bounds__(512)
void k_acc(const float* __restrict__ x, const int* __restrict__ bucket_cnt,
           const unsigned* __restrict__ buckets, float* __restrict__ out) {
    __shared__ unsigned srt[BCAP];               // 7 KB: src ids sorted by dst_low
    __shared__ int hist[BW];                     // histogram, then scatter cursor
    __shared__ int offs[BW + 1];                 // start offsets per node
    __shared__ int scan_tmp[BW];
    int tid = threadIdx.x;
    int b = blockIdx.x;
    int cnt = bucket_cnt[b];
    if (cnt > BCAP) cnt = BCAP;
    const unsigned* bk = buckets + (long long)b * BCAP;

    if (tid < BW) hist[tid] = 0;
    __syncthreads();

    // histogram of dst_low (scalar LDS atomics: ~1600 per block total)
    for (int k = tid; k < cnt; k += 512) atomicAdd(&hist[bk[k] & (BW - 1)], 1);
    __syncthreads();

    // Hillis-Steele inclusive scan over 128 counters
    if (tid < BW) scan_tmp[tid] = hist[tid];
    __syncthreads();
    for (int d = 1; d < BW; d <<= 1) {
        int v = 0;
        if (tid < BW && tid >= d) v = scan_tmp[tid - d];
        __syncthreads();
        if (tid < BW && tid >= d) scan_tmp[tid] += v;
        __syncthreads();
    }
    if (tid < BW) {
        offs[tid + 1] = scan_tmp[tid];
        if (tid == 0) offs[0] = 0;
        hist[tid] = 0;                           // reuse as cursor
    }
    __syncthreads();

    // scatter records into per-node sorted order (store src id)
    for (int k = tid; k < cnt; k += 512) {
        unsigned rec = bk[k];
        int d = rec & (BW - 1);
        int pos = atomicAdd(&hist[d], 1);
        srt[offs[d] + pos] = rec >> 7;
    }
    __syncthreads();

    // one wave per node: register accumulate (4-way MLP), plain coalesced store
    int wid = tid >> 6, lane = tid & 63;
    long long nbase = (long long)b * BW;
    for (int n = wid; n < BW; n += 8) {
        long long node = nbase + n;
        if (node >= N_NODES) break;              // wave-uniform
        int k0 = offs[n], k1 = offs[n + 1];
        float a0 = 0.f, a1 = 0.f, a2 = 0.f, a3 = 0.f;
        int k = k0;
        for (; k + 4 <= k1; k += 4) {
            a0 += x[(long long)srt[k]     * D_FEAT + lane];
            a1 += x[(long long)srt[k + 1] * D_FEAT + lane];
            a2 += x[(long long)srt[k + 2] * D_FEAT + lane];
            a3 += x[(long long)srt[k + 3] * D_FEAT + lane];
        }
        for (; k < k1; ++k) a0 += x[(long long)srt[k] * D_FEAT + lane];
        out[node * D_FEAT + lane] = (a0 + a1) + (a2 + a3);
    }
}

// ---------------- pass 3: rare spilled edges via atomics ----------------
__global__ __launch_bounds__(256)
void k_spill(const float* __restrict__ x, const int* __restrict__ spill_cnt,
             const int* __restrict__ spill, float* __restrict__ out) {
    int sc = *spill_cnt;
    if (sc > SPILL_CAP) sc = SPILL_CAP;
    int total = sc * D_FEAT;
    int stride = gridDim.x * blockDim.x;
    for (int i = blockIdx.x * blockDim.x + threadIdx.x; i < total; i += stride) {
        int p = i >> 6, f = i & 63;
        int d = spill[2 * p], s = spill[2 * p + 1];
        atomicAdd(&out[(long long)d * D_FEAT + f], x[(long long)s * D_FEAT + f]);
    }
}

// ---------------- fallback: direct atomic scatter ----------------
__global__ __launch_bounds__(256)
void mp_scatter_atomic(const float* __restrict__ x,
                       const int* __restrict__ src,
                       const int* __restrict__ dst,
                       float* __restrict__ out) {
    long long t = (long long)blockIdx.x * blockDim.x + threadIdx.x;
    long long e = t >> 6;
    int f = (int)(t & 63);
    if (e >= N_EDGES) return;
    atomicAdd(&out[(long long)dst[e] * D_FEAT + f],
              x[(long long)src[e] * D_FEAT + f]);
}

extern "C" void kernel_launch(void* const* d_in, const int* in_sizes, int n_in,
                              void* d_out, int out_size, void* d_ws, size_t ws_size,
                              hipStream_t stream) {
    const float* x   = (const float*)d_in[0];
    const int*   ei  = (const int*)d_in[1];   // (2, N_EDGES): row 0 = src, row 1 = dst
    const int*   src = ei;
    const int*   dst = ei + N_EDGES;
    float* out = (float*)d_out;

    // ws layout (ints): bucket_cnt[NBK] | spill_cnt[1] | spill[2*SPILL_CAP] | (align) | buckets[NBK*BCAP]
    const size_t BK_OFF   = ((size_t)NBK + 1 + 2 * SPILL_CAP + 63) & ~(size_t)63;
    const size_t WS_INTS  = BK_OFF + (size_t)NBK * BCAP;
    const size_t WS_BYTES = WS_INTS * sizeof(int);   // ~6.1 MB

    if (ws_size >= WS_BYTES) {
        int*      wsi        = (int*)d_ws;
        int*      bucket_cnt = wsi;
        int*      spill_cnt  = wsi + NBK;
        int*      spill      = wsi + NBK + 1;
        unsigned* buckets    = (unsigned*)(wsi + BK_OFF);

        hipMemsetAsync(bucket_cnt, 0, (size_t)(NBK + 1) * sizeof(int), stream);

        int grid_bin = (N_EDGES + CHUNK - 1) / CHUNK;     // 306
        k_bin<<<grid_bin, PASS1_T, 0, stream>>>(src, dst, bucket_cnt, buckets,
                                                spill_cnt, spill);

        k_acc<<<NBK, 512, 0, stream>>>(x, bucket_cnt, buckets, out);

        k_spill<<<32, 256, 0, stream>>>(x, spill_cnt, spill, out);
    } else {
        hipMemsetAsync(out, 0, (size_t)out_size * sizeof(float), stream);
        long long total = (long long)N_EDGES * D_FEAT;
        int block = 256;
        long long grid = (total + block - 1) / block;
        mp_scatter_atomic<<<(dim3)(unsigned)grid, block, 0, stream>>>(x, src, dst, out);
    }
}